// Round 13
// baseline (225.775 us; speedup 1.0000x reference)
//
#include <hip/hip_runtime.h>
#include <hip/hip_bf16.h>
#include <cmath>
#include <cstdint>

namespace {

constexpr int kB = 8;
constexpr int kS = 2048;
constexpr int kD = 1024;
constexpr int kN = kB * kS;          // 16384 rows
constexpr int kChunk = 32;
constexpr int kNChunk = kS / kChunk; // 64
constexpr float kEps = 1e-6f;

typedef __attribute__((ext_vector_type(8))) short bf16x8;
typedef __attribute__((ext_vector_type(4))) float f32x4;

__device__ inline float bf2f(short s) {
  union { unsigned u; float f; } c;
  c.u = ((unsigned)(unsigned short)s) << 16;
  return c.f;
}

struct bh4 { __hip_bfloat16 a, b, c, d; };  // 8-byte bf16 quad

// async global -> LDS, 16B per lane, wave-uniform LDS base (+lane*16)
__device__ inline void gload16(const void* g, void* l) {
  __builtin_amdgcn_global_load_lds(
      (const __attribute__((address_space(1))) void*)g,
      (__attribute__((address_space(3))) void*)l, 16, 0, 0);
}

// ---------------- block reduce (sum, sumsq) over 256 threads ---------------
// trailing __syncthreads so it is safe when called in a loop (WAR on r1/r2)
__device__ inline void blockReduce2(float& s1, float& s2) {
#pragma unroll
  for (int off = 32; off > 0; off >>= 1) {
    s1 += __shfl_down(s1, off);
    s2 += __shfl_down(s2, off);
  }
  __shared__ float r1[4], r2[4];
  int wid = threadIdx.x >> 6;
  if ((threadIdx.x & 63) == 0) { r1[wid] = s1; r2[wid] = s2; }
  __syncthreads();
  s1 = r1[0] + r1[1] + r1[2] + r1[3];
  s2 = r2[0] + r2[1] + r2[2] + r2[3];
  __syncthreads();
}

// ---------------- fused prep: LN(x), decay vectors, 3 transpose-casts -----
// grid: [0,kN) LN rows; [kN,kN+4) decay; [kN+4, kN+4+4096) transposes.
__global__ __launch_bounds__(256) void k_prep_ln(
    const float* __restrict__ x, const float* __restrict__ ln1w,
    const float* __restrict__ ln1b, __hip_bfloat16* __restrict__ xnb,
    const float* __restrict__ Wt, const float* __restrict__ Wo,
    const float* __restrict__ Wg, __hip_bfloat16* __restrict__ WtT,
    __hip_bfloat16* __restrict__ WoT, __hip_bfloat16* __restrict__ WgT,
    float* __restrict__ decay, float* __restrict__ dbeta,
    float* __restrict__ aL) {
  int b = blockIdx.x;
  int t = threadIdx.x;
  if (b < kN) {  // LayerNorm f32 -> bf16, 1 block = 1 row
    int row = b;
    const float4 v = reinterpret_cast<const float4*>(x + (size_t)row * kD)[t];
    float s1 = v.x + v.y + v.z + v.w;
    float s2 = v.x * v.x + v.y * v.y + v.z * v.z + v.w * v.w;
    blockReduce2(s1, s2);
    float mu = s1 * (1.0f / kD);
    float var = s2 * (1.0f / kD) - mu * mu;
    float rs = rsqrtf(var + kEps);
    float4 wv = reinterpret_cast<const float4*>(ln1w)[t];
    float4 bv = reinterpret_cast<const float4*>(ln1b)[t];
    bh4 o;
    o.a = __float2bfloat16((v.x - mu) * rs * wv.x + bv.x);
    o.b = __float2bfloat16((v.y - mu) * rs * wv.y + bv.y);
    o.c = __float2bfloat16((v.z - mu) * rs * wv.z + bv.z);
    o.d = __float2bfloat16((v.w - mu) * rs * wv.w + bv.w);
    reinterpret_cast<bh4*>(xnb + (size_t)row * kD)[t] = o;
    return;
  }
  b -= kN;
  if (b < 4) {  // decay vectors
    int h = b * 256 + t;
    float kk = 2.0f + 6.0f * (float)h / (float)(kD - 1);
    float d = exp2f(-1.0f / kk);        // 0.5^(1/k)
    decay[h] = d;
    dbeta[h] = 1.0f - d;
    aL[h] = exp2f(-(float)kChunk / kk); // decay^CHUNK
    return;
  }
  b -= 4;
  const float* W;
  __hip_bfloat16* WT;
  int K, local;
  if (b < 1024)      { W = Wt; WT = WtT; K = kD;     local = b; }
  else if (b < 2048) { W = Wo; WT = WoT; K = kD;     local = b - 1024; }
  else               { W = Wg; WT = WgT; K = 2 * kD; local = b - 2048; }
  int n0 = (local & 31) * 32, k0 = (local >> 5) * 32;
  __shared__ float tile[32][33];
  int tr = t >> 3, tc4 = (t & 7) * 4;
  float4 v = *reinterpret_cast<const float4*>(W + (size_t)(k0 + tr) * kD + n0 + tc4);
  tile[tc4 + 0][tr] = v.x;
  tile[tc4 + 1][tr] = v.y;
  tile[tc4 + 2][tr] = v.z;
  tile[tc4 + 3][tr] = v.w;
  __syncthreads();
  bh4 o;
  o.a = __float2bfloat16(tile[tr][tc4 + 0]);
  o.b = __float2bfloat16(tile[tr][tc4 + 1]);
  o.c = __float2bfloat16(tile[tr][tc4 + 2]);
  o.d = __float2bfloat16(tile[tr][tc4 + 3]);
  *reinterpret_cast<bh4*>(WT + (size_t)(n0 + tr) * K + k0 + tc4) = o;
}

// ---------------- bf16 MFMA GEMM, 256x256 tile, BK=64, 8 waves ------------
// Round-10 kernel (best measured: 968 TF, MfmaUtil 39%): 2-phase pipelined
// skeleton + coalescing-preserving LDS swizzle. Half-tile ROW-MAJOR
// [128][64] bf16, 16B slots XOR'd by row&7 (involution). Staging: lane l
// of a 1KB chunk (8 rows) fetches row l>>3, slot (l&7)^(l>>3) -> full
// aligned 128B rows per 8-lane group (coalesced; 16 cache lines/gload16).
// LDS dest linear (rule #21); fragment ds_read_b128 2-way = free (m136).
// Counted vmcnt(4) once per K-tile, never 0 in steady state (T4).
// Fused scan_ends (GEMM1 only), kChunk=32: each wave half = 4 chunks of 32
// rows; per chunk c2, ends = sum_{i<32} a^(31-i) u[i], i = mloc*16+kg*4+j,
// weights v[j]=a^(15-4kg-j), mloc=0 term carries extra a^16; kg-reduce via
// shfl_xor(16)+shfl_xor(32); lane kg==0 writes.
__global__ __launch_bounds__(512, 2) void k_mfma_gemm(
    const __hip_bfloat16* __restrict__ A1, const __hip_bfloat16* __restrict__ A2,
    const __hip_bfloat16* __restrict__ BT, int K,
    float* __restrict__ C, __hip_bfloat16* __restrict__ Cb,
    const float* __restrict__ colscale, const float* __restrict__ bias,
    float* __restrict__ ends, const float* __restrict__ decay) {
  __shared__ short As[2][2][8192];  // [dbuf][half][row*64 + swz-slot*8]
  __shared__ short Bs[2][2][8192];
  const int t = threadIdx.x;
  const int wid = t >> 6, lane = t & 63;
  // bijective XCD swizzle (nwg == 256, % 8 == 0)
  const int nwg = gridDim.x;
  const int bid = blockIdx.x;
  const int s = (bid & 7) * (nwg >> 3) + (bid >> 3);
  const int bn = (s & 3) * 256;   // 4 column tiles (kD/256)
  const int bm = (s >> 2) * 256;
  const int wr = wid >> 2;        // 0..1  (M dir; owns A half wr)
  const int wcn = wid & 3;        // 0..3  (N dir; reads B half wcn>>1)
  const int r = lane & 15, kg = lane >> 4;
  const int NT = K / 64;

  // staging source map: row within 8-row chunk, swizzled 16B slot
  const int srow = lane >> 3;                       // 0..7
  const int scol = (((lane & 7) ^ srow)) * 8;       // shorts (16B units)

  auto stageA = [&](int kt, int h) {
    const __hip_bfloat16* Asrc = A1;
    int kk = kt * 64;
    if (A2 && kk >= kD) { Asrc = A2; kk -= kD; }
    short* dst = &As[kt & 1][h][0];
#pragma unroll
    for (int j = 0; j < 2; ++j) {
      int chunk = wid * 2 + j;            // 0..15, 8 rows each
      int row = chunk * 8 + srow;
      gload16(Asrc + (size_t)(bm + h * 128 + row) * kD + kk + scol,
              dst + chunk * 512 + lane * 8);
    }
  };
  auto stageB = [&](int kt, int h) {
    short* dst = &Bs[kt & 1][h][0];
#pragma unroll
    for (int j = 0; j < 2; ++j) {
      int chunk = wid * 2 + j;
      int row = chunk * 8 + srow;
      gload16(BT + (size_t)(bn + h * 128 + row) * K + kt * 64 + scol,
              dst + chunk * 512 + lane * 8);
    }
  };

  f32x4 acc[8][4];
#pragma unroll
  for (int m = 0; m < 8; ++m)
#pragma unroll
    for (int n = 0; n < 4; ++n) acc[m][n] = (f32x4){0.f, 0.f, 0.f, 0.f};

  // prologue: tile 0 fully + B of tile 1 (12 loads/wave); wait tile 0 only
  stageA(0, 0); stageA(0, 1); stageB(0, 0); stageB(0, 1);
  stageB(1, 0); stageB(1, 1);
  asm volatile("s_waitcnt vmcnt(4)" ::: "memory");  // tile 0 landed
  __builtin_amdgcn_s_barrier();
  asm volatile("" ::: "memory");

  for (int T = 0; T < NT; ++T) {
    const int bc = T & 1;
    const char* Ab = reinterpret_cast<const char*>(&As[bc][wr][0]);
    const char* Bb = reinterpret_cast<const char*>(&Bs[bc][wcn >> 1][0]);
    const int bcol = (wcn & 1) * 64;
    bf16x8 bfr[4][2], aLO[4][2], aHI[4][2];
    // ================= phase A =================
#pragma unroll
    for (int n = 0; n < 4; ++n)
#pragma unroll
      for (int ks = 0; ks < 2; ++ks) {
        int row = bcol + n * 16 + r;
        int slot = (ks * 4 + kg) ^ (r & 7);
        bfr[n][ks] = *reinterpret_cast<const bf16x8*>(Bb + row * 128 + slot * 16);
      }
#pragma unroll
    for (int mm = 0; mm < 4; ++mm)
#pragma unroll
      for (int ks = 0; ks < 2; ++ks) {
        int row = mm * 16 + r;
        int slot = (ks * 4 + kg) ^ (r & 7);
        aLO[mm][ks] = *reinterpret_cast<const bf16x8*>(Ab + row * 128 + slot * 16);
      }
    if (T + 1 < NT) { stageA(T + 1, 0); stageA(T + 1, 1); }
    asm volatile("" ::: "memory");
    __builtin_amdgcn_s_barrier();
    asm volatile("" ::: "memory");
    __builtin_amdgcn_s_setprio(1);
#pragma unroll
    for (int mm = 0; mm < 4; ++mm)
#pragma unroll
      for (int n = 0; n < 4; ++n)
#pragma unroll
        for (int ks = 0; ks < 2; ++ks)
          acc[mm][n] = __builtin_amdgcn_mfma_f32_16x16x32_bf16(
              aLO[mm][ks], bfr[n][ks], acc[mm][n], 0, 0, 0);
    __builtin_amdgcn_s_setprio(0);
    asm volatile("" ::: "memory");
    __builtin_amdgcn_s_barrier();
    asm volatile("" ::: "memory");
    // ================= phase B =================
#pragma unroll
    for (int mm = 0; mm < 4; ++mm)
#pragma unroll
      for (int ks = 0; ks < 2; ++ks) {
        int row = (mm + 4) * 16 + r;
        int slot = (ks * 4 + kg) ^ (r & 7);
        aHI[mm][ks] = *reinterpret_cast<const bf16x8*>(Ab + row * 128 + slot * 16);
      }
    if (T + 2 < NT) { stageB(T + 2, 0); stageB(T + 2, 1); }
    asm volatile("" ::: "memory");
    __builtin_amdgcn_s_barrier();
    asm volatile("" ::: "memory");
    __builtin_amdgcn_s_setprio(1);
#pragma unroll
    for (int mm = 0; mm < 4; ++mm)
#pragma unroll
      for (int n = 0; n < 4; ++n)
#pragma unroll
        for (int ks = 0; ks < 2; ++ks)
          acc[mm + 4][n] = __builtin_amdgcn_mfma_f32_16x16x32_bf16(
              aHI[mm][ks], bfr[n][ks], acc[mm + 4][n], 0, 0, 0);
    __builtin_amdgcn_s_setprio(0);
    if (T + 2 < NT)
      asm volatile("s_waitcnt vmcnt(4)" ::: "memory");  // A(T+1) landed
    else if (T + 1 < NT)
      asm volatile("s_waitcnt vmcnt(0)" ::: "memory");  // last prefetch
    asm volatile("" ::: "memory");
    __builtin_amdgcn_s_barrier();
    asm volatile("" ::: "memory");
  }

  // epilogue: D[row = kg*4+j][col = r] per fragment (m89-verified mapping)
  int col[4];
  float cs[4], bi[4];
#pragma unroll
  for (int n = 0; n < 4; ++n) {
    col[n] = bn + wcn * 64 + n * 16 + r;
    cs[n] = colscale ? colscale[col[n]] : 1.0f;
    bi[n] = bias ? bias[col[n]] : 0.0f;
  }
#pragma unroll
  for (int m = 0; m < 8; ++m) {
#pragma unroll
    for (int j = 0; j < 4; ++j) {
      int row = bm + wr * 128 + m * 16 + kg * 4 + j;
#pragma unroll
      for (int n = 0; n < 4; ++n) {
        float v = acc[m][n][j] * cs[n] + bi[n];
        if (C) C[(size_t)row * kD + col[n]] = v;
        if (Cb) Cb[(size_t)row * kD + col[n]] = __float2bfloat16(v);
      }
    }
  }

  // fused scan_ends (GEMM1 only), kChunk=32: wave half = 4 chunks of 32 rows
  if (ends) {
    const int row0 = bm + wr * 128;
    const int chunk0 = row0 >> 5;       // global 32-row chunk index
#pragma unroll
    for (int n = 0; n < 4; ++n) {
      float a = decay[col[n]];
      float a2 = a * a, a4 = a2 * a2, a8 = a4 * a4, a16 = a8 * a8;
      // v[j] = a^(15 - 4*kg - j)
      float pw = (kg == 3) ? 1.0f
               : (kg == 2) ? a4
               : (kg == 1) ? a4 * a4
                           : a4 * a4 * a4;
      float v3 = pw, v2 = pw * a, v1 = pw * a2, v0 = pw * a2 * a;
      const float vj[4] = {v0, v1, v2, v3};
#pragma unroll
      for (int c2 = 0; c2 < 4; ++c2) {
        float p = 0.f;
#pragma unroll
        for (int j = 0; j < 4; ++j) {
          float u0 = acc[2 * c2][n][j] * cs[n] + bi[n];      // i = kg*4+j
          float u1 = acc[2 * c2 + 1][n][j] * cs[n] + bi[n];  // i = 16+kg*4+j
          p += vj[j] * (a16 * u0 + u1);
        }
        p += __shfl_xor(p, 16);
        p += __shfl_xor(p, 32);
        if (kg == 0) ends[(size_t)(chunk0 + c2) * kD + col[n]] = p;
      }
    }
  }
}

// ---------------- scan carries across chunks (64 chunks of 32) ------------
__global__ __launch_bounds__(256) void k_scan_carry(
    const float* __restrict__ ends, const float* __restrict__ aL,
    float* __restrict__ carry) {
  int tid = blockIdx.x * blockDim.x + threadIdx.x;  // [0, B*D)
  int h = tid & (kD - 1);
  int b = tid >> 10;
  float al = aL[h];
  float car = 0.f;
#pragma unroll
  for (int c = 0; c < kNChunk; ++c) {
    size_t idx = ((size_t)(b * kNChunk + c)) * kD + h;
    carry[idx] = car;
    car = fmaf(al, car, ends[idx]);
  }
}

// ---------------- fused rescan + LayerNorm: u -> cxn = LN(cx) bf16 --------
// block = one (b, chunk): 32 rows x 1024 h; 256 threads x 4 h each.
// Recurrence per h independent; per-row stats via blockReduce2 on the f32
// pre-rounding values; cx itself is DEAD after LN -> never materialized
// (saves 67 MB of traffic + one launch vs separate apply + LN kernels).
__global__ __launch_bounds__(256) void k_scan_apply_ln(
    const __hip_bfloat16* __restrict__ u, const float* __restrict__ decay,
    const float* __restrict__ carry, const float* __restrict__ lnw,
    const float* __restrict__ lnb, __hip_bfloat16* __restrict__ cxn) {
  const int blk = blockIdx.x;           // b*64 + c
  const int t = threadIdx.x;
  const int h0 = t * 4;
  const int b = blk >> 6, c = blk & 63;
  const size_t rowbase = (size_t)b * kS + (size_t)c * kChunk;  // first row

  float a0 = decay[h0], a1 = decay[h0 + 1], a2 = decay[h0 + 2],
        a3 = decay[h0 + 3];
  const float4 cv = *reinterpret_cast<const float4*>(
      carry + (size_t)blk * kD + h0);
  float v0 = cv.x, v1 = cv.y, v2 = cv.z, v3 = cv.w;
  const float4 wv = *reinterpret_cast<const float4*>(lnw + h0);
  const float4 bv = *reinterpret_cast<const float4*>(lnb + h0);

  for (int i = 0; i < kChunk; ++i) {
    short4 q = *reinterpret_cast<const short4*>(u + (rowbase + i) * kD + h0);
    v0 = fmaf(a0, v0, bf2f(q.x));
    v1 = fmaf(a1, v1, bf2f(q.y));
    v2 = fmaf(a2, v2, bf2f(q.z));
    v3 = fmaf(a3, v3, bf2f(q.w));
    float s1 = v0 + v1 + v2 + v3;
    float s2 = v0 * v0 + v1 * v1 + v2 * v2 + v3 * v3;
    blockReduce2(s1, s2);
    float mu = s1 * (1.0f / kD);
    float var = s2 * (1.0f / kD) - mu * mu;
    float rs = rsqrtf(var + kEps);
    bh4 o;
    o.a = __float2bfloat16((v0 - mu) * rs * wv.x + bv.x);
    o.b = __float2bfloat16((v1 - mu) * rs * wv.y + bv.y);
    o.c = __float2bfloat16((v2 - mu) * rs * wv.z + bv.z);
    o.d = __float2bfloat16((v3 - mu) * rs * wv.w + bv.w);
    *reinterpret_cast<bh4*>(cxn + (rowbase + i) * kD + h0) = o;
  }
}

// ---------------- final: LN(gpre) -> sigmoid -> blend ---------------------
__global__ __launch_bounds__(256) void k_final(
    const __hip_bfloat16* __restrict__ gpre, const __hip_bfloat16* __restrict__ res,
    const __hip_bfloat16* __restrict__ outp, const float* __restrict__ w,
    const float* __restrict__ b, float* __restrict__ y) {
  int row = blockIdx.x;
  int t = threadIdx.x;
  short4 q = reinterpret_cast<const short4*>(gpre + (size_t)row * kD)[t];
  float vv[4] = {bf2f(q.x), bf2f(q.y), bf2f(q.z), bf2f(q.w)};
  float s1 = vv[0] + vv[1] + vv[2] + vv[3];
  float s2 = vv[0] * vv[0] + vv[1] * vv[1] + vv[2] * vv[2] + vv[3] * vv[3];
  blockReduce2(s1, s2);
  float mu = s1 * (1.0f / kD);
  float var = s2 * (1.0f / kD) - mu * mu;
  float rs = rsqrtf(var + kEps);
  float4 wv = reinterpret_cast<const float4*>(w)[t];
  float4 bv = reinterpret_cast<const float4*>(b)[t];
  short4 r4 = reinterpret_cast<const short4*>(res + (size_t)row * kD)[t];
  short4 o4 = reinterpret_cast<const short4*>(outp + (size_t)row * kD)[t];
  float rr[4] = {bf2f(r4.x), bf2f(r4.y), bf2f(r4.z), bf2f(r4.w)};
  float oo[4] = {bf2f(o4.x), bf2f(o4.y), bf2f(o4.z), bf2f(o4.w)};
  float ww[4] = {wv.x, wv.y, wv.z, wv.w};
  float bb[4] = {bv.x, bv.y, bv.z, bv.w};
  float4 out;
  float* op = &out.x;
#pragma unroll
  for (int i = 0; i < 4; ++i) {
    float z = (vv[i] - mu) * rs * ww[i] + bb[i];
    float g = 1.0f / (1.0f + expf(-z));
    op[i] = rr[i] + g * (oo[i] - rr[i]);
  }
  reinterpret_cast<float4*>(y + (size_t)row * kD)[t] = out;
}

}  // namespace

extern "C" void kernel_launch(void* const* d_in, const int* in_sizes, int n_in,
                              void* d_out, int out_size, void* d_ws,
                              size_t ws_size, hipStream_t stream) {
  const float* x = (const float*)d_in[0];
  const float* Wt = (const float*)d_in[1];
  const float* Wo = (const float*)d_in[2];
  const float* Wg = (const float*)d_in[3];
  const float* bg = (const float*)d_in[4];
  const float* ln1w = (const float*)d_in[5];
  const float* ln1b = (const float*)d_in[6];
  const float* lncw = (const float*)d_in[7];
  const float* lncb = (const float*)d_in[8];
  const float* lngw = (const float*)d_in[9];
  const float* lngb = (const float*)d_in[10];
  float* y = (float*)d_out;

  char* ws = (char*)d_ws;
  size_t off = 0;
  auto alloc = [&](size_t bytes) {
    char* p = ws + off;
    off += (bytes + 255) & ~(size_t)255;
    return p;
  };
  __hip_bfloat16* xnb = (__hip_bfloat16*)alloc((size_t)kN * kD * 2);  // _x (res)
  __hip_bfloat16* ub = (__hip_bfloat16*)alloc((size_t)kN * kD * 2);   // u -> gpre
  __hip_bfloat16* outb = (__hip_bfloat16*)alloc((size_t)kN * kD * 2); // out
  __hip_bfloat16* cxn = (__hip_bfloat16*)alloc((size_t)kN * kD * 2);  // LN(cx)
  __hip_bfloat16* WtT = (__hip_bfloat16*)alloc((size_t)kD * kD * 2);
  __hip_bfloat16* WoT = (__hip_bfloat16*)alloc((size_t)kD * kD * 2);
  __hip_bfloat16* WgT = (__hip_bfloat16*)alloc((size_t)kD * 2 * kD * 2);
  float* decay = (float*)alloc(kD * 4);
  float* dbeta = (float*)alloc(kD * 4);
  float* aL = (float*)alloc(kD * 4);
  float* ends = (float*)alloc((size_t)kB * kNChunk * kD * 4);   // 2MB
  float* carry = (float*)alloc((size_t)kB * kNChunk * kD * 4);  // 2MB

  const int nwg = (kD / 256) * (kN / 256);  // 4 * 64 = 256, % 8 == 0

  // fused: LN(x) + decay + weight transpose-casts (one launch)
  k_prep_ln<<<kN + 4 + 4096, 256, 0, stream>>>(
      x, ln1w, ln1b, xnb, Wt, Wo, Wg, WtT, WoT, WgT, decay, dbeta, aL);
  // u = (_x @ Wt) * decay_beta (bf16 out) + fused scan_ends (32-row chunks)
  k_mfma_gemm<<<nwg, 512, 0, stream>>>(xnb, nullptr, WtT, kD, nullptr, ub,
                                       dbeta, nullptr, ends, decay);
  // scan carries (64 chunks)
  k_scan_carry<<<(kB * kD) / 256, 256, 0, stream>>>(ends, aL, carry);
  // fused rescan + LN: u -> cxn = LN(cx) directly (cx never materialized)
  k_scan_apply_ln<<<kB * kNChunk, 256, 0, stream>>>(ub, decay, carry, lncw,
                                                    lncb, cxn);
  // out = LN(cx) @ Wo  (bf16 out)
  k_mfma_gemm<<<nwg, 512, 0, stream>>>(cxn, nullptr, WoT, kD, nullptr, outb,
                                       nullptr, nullptr, nullptr, nullptr);
  // gpre = concat(_x, out) @ Wg + bg  (bf16 out, overwrites ub; u dead)
  k_mfma_gemm<<<nwg, 512, 0, stream>>>(xnb, outb, WgT, 2 * kD, nullptr, ub,
                                       nullptr, bg, nullptr, nullptr);
  // y = res + sigmoid(LN(gpre)) * (out - res)
  k_final<<<kN, 256, 0, stream>>>(ub, xnb, outb, lngw, lngb, y);
}

// Round 14
// 218.820 us; speedup vs baseline: 1.0318x; 1.0318x over previous
//
#include <hip/hip_runtime.h>
#include <hip/hip_bf16.h>
#include <cmath>
#include <cstdint>

namespace {

constexpr int kB = 8;
constexpr int kS = 2048;
constexpr int kD = 1024;
constexpr int kN = kB * kS;          // 16384 rows
constexpr int kChunk = 32;
constexpr int kNChunk = kS / kChunk; // 64
constexpr float kEps = 1e-6f;

typedef __attribute__((ext_vector_type(8))) short bf16x8;
typedef __attribute__((ext_vector_type(4))) float f32x4;

__device__ inline float bf2f(short s) {
  union { unsigned u; float f; } c;
  c.u = ((unsigned)(unsigned short)s) << 16;
  return c.f;
}

struct bh4 { __hip_bfloat16 a, b, c, d; };  // 8-byte bf16 quad

// async global -> LDS, 16B per lane, wave-uniform LDS base (+lane*16)
__device__ inline void gload16(const void* g, void* l) {
  __builtin_amdgcn_global_load_lds(
      (const __attribute__((address_space(1))) void*)g,
      (__attribute__((address_space(3))) void*)l, 16, 0, 0);
}

// ---------------- block reduce (sum, sumsq) over 256 threads ---------------
__device__ inline void blockReduce2(float& s1, float& s2) {
#pragma unroll
  for (int off = 32; off > 0; off >>= 1) {
    s1 += __shfl_down(s1, off);
    s2 += __shfl_down(s2, off);
  }
  __shared__ float r1[4], r2[4];
  int wid = threadIdx.x >> 6;
  if ((threadIdx.x & 63) == 0) { r1[wid] = s1; r2[wid] = s2; }
  __syncthreads();
  s1 = r1[0] + r1[1] + r1[2] + r1[3];
  s2 = r2[0] + r2[1] + r2[2] + r2[3];
}

// ---------------- fused prep: LN(x), decay vectors, 3 transpose-casts -----
// grid: [0,kN) LN rows; [kN,kN+4) decay; [kN+4, kN+4+4096) transposes.
__global__ __launch_bounds__(256) void k_prep_ln(
    const float* __restrict__ x, const float* __restrict__ ln1w,
    const float* __restrict__ ln1b, __hip_bfloat16* __restrict__ xnb,
    const float* __restrict__ Wt, const float* __restrict__ Wo,
    const float* __restrict__ Wg, __hip_bfloat16* __restrict__ WtT,
    __hip_bfloat16* __restrict__ WoT, __hip_bfloat16* __restrict__ WgT,
    float* __restrict__ decay, float* __restrict__ dbeta,
    float* __restrict__ aL) {
  int b = blockIdx.x;
  int t = threadIdx.x;
  if (b < kN) {  // LayerNorm f32 -> bf16, 1 block = 1 row
    int row = b;
    const float4 v = reinterpret_cast<const float4*>(x + (size_t)row * kD)[t];
    float s1 = v.x + v.y + v.z + v.w;
    float s2 = v.x * v.x + v.y * v.y + v.z * v.z + v.w * v.w;
    blockReduce2(s1, s2);
    float mu = s1 * (1.0f / kD);
    float var = s2 * (1.0f / kD) - mu * mu;
    float rs = rsqrtf(var + kEps);
    float4 wv = reinterpret_cast<const float4*>(ln1w)[t];
    float4 bv = reinterpret_cast<const float4*>(ln1b)[t];
    bh4 o;
    o.a = __float2bfloat16((v.x - mu) * rs * wv.x + bv.x);
    o.b = __float2bfloat16((v.y - mu) * rs * wv.y + bv.y);
    o.c = __float2bfloat16((v.z - mu) * rs * wv.z + bv.z);
    o.d = __float2bfloat16((v.w - mu) * rs * wv.w + bv.w);
    reinterpret_cast<bh4*>(xnb + (size_t)row * kD)[t] = o;
    return;
  }
  b -= kN;
  if (b < 4) {  // decay vectors
    int h = b * 256 + t;
    float kk = 2.0f + 6.0f * (float)h / (float)(kD - 1);
    float d = exp2f(-1.0f / kk);        // 0.5^(1/k)
    decay[h] = d;
    dbeta[h] = 1.0f - d;
    aL[h] = exp2f(-(float)kChunk / kk); // decay^CHUNK
    return;
  }
  b -= 4;
  const float* W;
  __hip_bfloat16* WT;
  int K, local;
  if (b < 1024)      { W = Wt; WT = WtT; K = kD;     local = b; }
  else if (b < 2048) { W = Wo; WT = WoT; K = kD;     local = b - 1024; }
  else               { W = Wg; WT = WgT; K = 2 * kD; local = b - 2048; }
  int n0 = (local & 31) * 32, k0 = (local >> 5) * 32;
  __shared__ float tile[32][33];
  int tr = t >> 3, tc4 = (t & 7) * 4;
  float4 v = *reinterpret_cast<const float4*>(W + (size_t)(k0 + tr) * kD + n0 + tc4);
  tile[tc4 + 0][tr] = v.x;
  tile[tc4 + 1][tr] = v.y;
  tile[tc4 + 2][tr] = v.z;
  tile[tc4 + 3][tr] = v.w;
  __syncthreads();
  bh4 o;
  o.a = __float2bfloat16(tile[tr][tc4 + 0]);
  o.b = __float2bfloat16(tile[tr][tc4 + 1]);
  o.c = __float2bfloat16(tile[tr][tc4 + 2]);
  o.d = __float2bfloat16(tile[tr][tc4 + 3]);
  *reinterpret_cast<bh4*>(WT + (size_t)(n0 + tr) * K + k0 + tc4) = o;
}

// ---------------- bf16 MFMA GEMM, 256x256 tile, BK=64, 8 waves ------------
// Round-10 kernel (best measured: 968 TF, MfmaUtil 39%): 2-phase pipelined
// skeleton + coalescing-preserving LDS swizzle. Half-tile ROW-MAJOR
// [128][64] bf16, 16B slots XOR'd by row&7 (involution). Staging: lane l
// of a 1KB chunk (8 rows) fetches row l>>3, slot (l&7)^(l>>3) -> full
// aligned 128B rows per 8-lane group (coalesced; 16 cache lines/gload16).
// LDS dest linear (rule #21); fragment ds_read_b128 2-way = free (m136).
// Counted vmcnt(4) once per K-tile, never 0 in steady state (T4).
// Fused scan_ends (GEMM1 only), kChunk=32: each wave half = 4 chunks of 32
// rows; per chunk c2, ends = sum_{i<32} a^(31-i) u[i], i = mloc*16+kg*4+j,
// weights v[j]=a^(15-4kg-j), mloc=0 term carries extra a^16; kg-reduce via
// shfl_xor(16)+shfl_xor(32); lane kg==0 writes.
__global__ __launch_bounds__(512, 2) void k_mfma_gemm(
    const __hip_bfloat16* __restrict__ A1, const __hip_bfloat16* __restrict__ A2,
    const __hip_bfloat16* __restrict__ BT, int K,
    float* __restrict__ C, __hip_bfloat16* __restrict__ Cb,
    const float* __restrict__ colscale, const float* __restrict__ bias,
    float* __restrict__ ends, const float* __restrict__ decay) {
  __shared__ short As[2][2][8192];  // [dbuf][half][row*64 + swz-slot*8]
  __shared__ short Bs[2][2][8192];
  const int t = threadIdx.x;
  const int wid = t >> 6, lane = t & 63;
  // bijective XCD swizzle (nwg == 256, % 8 == 0)
  const int nwg = gridDim.x;
  const int bid = blockIdx.x;
  const int s = (bid & 7) * (nwg >> 3) + (bid >> 3);
  const int bn = (s & 3) * 256;   // 4 column tiles (kD/256)
  const int bm = (s >> 2) * 256;
  const int wr = wid >> 2;        // 0..1  (M dir; owns A half wr)
  const int wcn = wid & 3;        // 0..3  (N dir; reads B half wcn>>1)
  const int r = lane & 15, kg = lane >> 4;
  const int NT = K / 64;

  // staging source map: row within 8-row chunk, swizzled 16B slot
  const int srow = lane >> 3;                       // 0..7
  const int scol = (((lane & 7) ^ srow)) * 8;       // shorts (16B units)

  auto stageA = [&](int kt, int h) {
    const __hip_bfloat16* Asrc = A1;
    int kk = kt * 64;
    if (A2 && kk >= kD) { Asrc = A2; kk -= kD; }
    short* dst = &As[kt & 1][h][0];
#pragma unroll
    for (int j = 0; j < 2; ++j) {
      int chunk = wid * 2 + j;            // 0..15, 8 rows each
      int row = chunk * 8 + srow;
      gload16(Asrc + (size_t)(bm + h * 128 + row) * kD + kk + scol,
              dst + chunk * 512 + lane * 8);
    }
  };
  auto stageB = [&](int kt, int h) {
    short* dst = &Bs[kt & 1][h][0];
#pragma unroll
    for (int j = 0; j < 2; ++j) {
      int chunk = wid * 2 + j;
      int row = chunk * 8 + srow;
      gload16(BT + (size_t)(bn + h * 128 + row) * K + kt * 64 + scol,
              dst + chunk * 512 + lane * 8);
    }
  };

  f32x4 acc[8][4];
#pragma unroll
  for (int m = 0; m < 8; ++m)
#pragma unroll
    for (int n = 0; n < 4; ++n) acc[m][n] = (f32x4){0.f, 0.f, 0.f, 0.f};

  // prologue: tile 0 fully + B of tile 1 (12 loads/wave); wait tile 0 only
  stageA(0, 0); stageA(0, 1); stageB(0, 0); stageB(0, 1);
  stageB(1, 0); stageB(1, 1);
  asm volatile("s_waitcnt vmcnt(4)" ::: "memory");  // tile 0 landed
  __builtin_amdgcn_s_barrier();
  asm volatile("" ::: "memory");

  for (int T = 0; T < NT; ++T) {
    const int bc = T & 1;
    const char* Ab = reinterpret_cast<const char*>(&As[bc][wr][0]);
    const char* Bb = reinterpret_cast<const char*>(&Bs[bc][wcn >> 1][0]);
    const int bcol = (wcn & 1) * 64;
    bf16x8 bfr[4][2], aLO[4][2], aHI[4][2];
    // ================= phase A =================
#pragma unroll
    for (int n = 0; n < 4; ++n)
#pragma unroll
      for (int ks = 0; ks < 2; ++ks) {
        int row = bcol + n * 16 + r;
        int slot = (ks * 4 + kg) ^ (r & 7);
        bfr[n][ks] = *reinterpret_cast<const bf16x8*>(Bb + row * 128 + slot * 16);
      }
#pragma unroll
    for (int mm = 0; mm < 4; ++mm)
#pragma unroll
      for (int ks = 0; ks < 2; ++ks) {
        int row = mm * 16 + r;
        int slot = (ks * 4 + kg) ^ (r & 7);
        aLO[mm][ks] = *reinterpret_cast<const bf16x8*>(Ab + row * 128 + slot * 16);
      }
    if (T + 1 < NT) { stageA(T + 1, 0); stageA(T + 1, 1); }
    asm volatile("" ::: "memory");
    __builtin_amdgcn_s_barrier();
    asm volatile("" ::: "memory");
    __builtin_amdgcn_s_setprio(1);
#pragma unroll
    for (int mm = 0; mm < 4; ++mm)
#pragma unroll
      for (int n = 0; n < 4; ++n)
#pragma unroll
        for (int ks = 0; ks < 2; ++ks)
          acc[mm][n] = __builtin_amdgcn_mfma_f32_16x16x32_bf16(
              aLO[mm][ks], bfr[n][ks], acc[mm][n], 0, 0, 0);
    __builtin_amdgcn_s_setprio(0);
    asm volatile("" ::: "memory");
    __builtin_amdgcn_s_barrier();
    asm volatile("" ::: "memory");
    // ================= phase B =================
#pragma unroll
    for (int mm = 0; mm < 4; ++mm)
#pragma unroll
      for (int ks = 0; ks < 2; ++ks) {
        int row = (mm + 4) * 16 + r;
        int slot = (ks * 4 + kg) ^ (r & 7);
        aHI[mm][ks] = *reinterpret_cast<const bf16x8*>(Ab + row * 128 + slot * 16);
      }
    if (T + 2 < NT) { stageB(T + 2, 0); stageB(T + 2, 1); }
    asm volatile("" ::: "memory");
    __builtin_amdgcn_s_barrier();
    asm volatile("" ::: "memory");
    __builtin_amdgcn_s_setprio(1);
#pragma unroll
    for (int mm = 0; mm < 4; ++mm)
#pragma unroll
      for (int n = 0; n < 4; ++n)
#pragma unroll
        for (int ks = 0; ks < 2; ++ks)
          acc[mm + 4][n] = __builtin_amdgcn_mfma_f32_16x16x32_bf16(
              aHI[mm][ks], bfr[n][ks], acc[mm + 4][n], 0, 0, 0);
    __builtin_amdgcn_s_setprio(0);
    if (T + 2 < NT)
      asm volatile("s_waitcnt vmcnt(4)" ::: "memory");  // A(T+1) landed
    else if (T + 1 < NT)
      asm volatile("s_waitcnt vmcnt(0)" ::: "memory");  // last prefetch
    asm volatile("" ::: "memory");
    __builtin_amdgcn_s_barrier();
    asm volatile("" ::: "memory");
  }

  // epilogue: D[row = kg*4+j][col = r] per fragment (m89-verified mapping)
  int col[4];
  float cs[4], bi[4];
#pragma unroll
  for (int n = 0; n < 4; ++n) {
    col[n] = bn + wcn * 64 + n * 16 + r;
    cs[n] = colscale ? colscale[col[n]] : 1.0f;
    bi[n] = bias ? bias[col[n]] : 0.0f;
  }
#pragma unroll
  for (int m = 0; m < 8; ++m) {
#pragma unroll
    for (int j = 0; j < 4; ++j) {
      int row = bm + wr * 128 + m * 16 + kg * 4 + j;
#pragma unroll
      for (int n = 0; n < 4; ++n) {
        float v = acc[m][n][j] * cs[n] + bi[n];
        if (C) C[(size_t)row * kD + col[n]] = v;
        if (Cb) Cb[(size_t)row * kD + col[n]] = __float2bfloat16(v);
      }
    }
  }

  // fused scan_ends (GEMM1 only), kChunk=32: wave half = 4 chunks of 32 rows
  if (ends) {
    const int row0 = bm + wr * 128;
    const int chunk0 = row0 >> 5;       // global 32-row chunk index
#pragma unroll
    for (int n = 0; n < 4; ++n) {
      float a = decay[col[n]];
      float a2 = a * a, a4 = a2 * a2, a8 = a4 * a4, a16 = a8 * a8;
      // v[j] = a^(15 - 4*kg - j)
      float pw = (kg == 3) ? 1.0f
               : (kg == 2) ? a4
               : (kg == 1) ? a4 * a4
                           : a4 * a4 * a4;
      float v3 = pw, v2 = pw * a, v1 = pw * a2, v0 = pw * a2 * a;
      const float vj[4] = {v0, v1, v2, v3};
#pragma unroll
      for (int c2 = 0; c2 < 4; ++c2) {
        float p = 0.f;
#pragma unroll
        for (int j = 0; j < 4; ++j) {
          float u0 = acc[2 * c2][n][j] * cs[n] + bi[n];      // i = kg*4+j
          float u1 = acc[2 * c2 + 1][n][j] * cs[n] + bi[n];  // i = 16+kg*4+j
          p += vj[j] * (a16 * u0 + u1);
        }
        p += __shfl_xor(p, 16);
        p += __shfl_xor(p, 32);
        if (kg == 0) ends[(size_t)(chunk0 + c2) * kD + col[n]] = p;
      }
    }
  }
}

// ---------------- scan carries across chunks (64 chunks of 32) ------------
__global__ __launch_bounds__(256) void k_scan_carry(
    const float* __restrict__ ends, const float* __restrict__ aL,
    float* __restrict__ carry) {
  int tid = blockIdx.x * blockDim.x + threadIdx.x;  // [0, B*D)
  int h = tid & (kD - 1);
  int b = tid >> 10;
  float al = aL[h];
  float car = 0.f;
#pragma unroll
  for (int c = 0; c < kNChunk; ++c) {
    size_t idx = ((size_t)(b * kNChunk + c)) * kD + h;
    carry[idx] = car;
    car = fmaf(al, car, ends[idx]);
  }
}

// ---------------- fused rescan + LayerNorm, 3-pass / 2-barrier ------------
// block = one (b, chunk): 32 rows x 1024 h; 256 threads x 4 h each.
// Pass 1: per-h scan (thread-local recurrence), park bf16 cx in padded LDS
//         [32][1032] (2064B rows; plain ds_write -> padding legal).
// Pass 2: per-row stats, 8 lanes/row x 128 h, 3x intra-group shfl_xor
//         (no barriers), mu/rstd -> 32-entry LDS arrays.
// Pass 3: LN + coalesced global write with the pass-1 mapping (LDS read of
//         own 8B + broadcast stats).
// Replaces r13's per-row blockReduce2 (64 barriers/block -> 2).
__global__ __launch_bounds__(256) void k_scan_apply_ln(
    const __hip_bfloat16* __restrict__ u, const float* __restrict__ decay,
    const float* __restrict__ carry, const float* __restrict__ lnw,
    const float* __restrict__ lnb, __hip_bfloat16* __restrict__ cxn) {
  constexpr int PADH = kD + 8;            // 1032 shorts = 2064B rows
  __shared__ short cxs[kChunk * PADH];    // 66 KB
  __shared__ float smu[kChunk], srs[kChunk];
  const int blk = blockIdx.x;             // b*64 + c
  const int t = threadIdx.x;
  const int h0 = t * 4;
  const int b = blk >> 6, c = blk & 63;
  const size_t rowbase = (size_t)b * kS + (size_t)c * kChunk;  // first row

  // ---- pass 1: scan ----
  {
    float a0 = decay[h0], a1 = decay[h0 + 1], a2 = decay[h0 + 2],
          a3 = decay[h0 + 3];
    const float4 cv = *reinterpret_cast<const float4*>(
        carry + (size_t)blk * kD + h0);
    float v0 = cv.x, v1 = cv.y, v2 = cv.z, v3 = cv.w;
#pragma unroll 4
    for (int i = 0; i < kChunk; ++i) {
      short4 q = *reinterpret_cast<const short4*>(u + (rowbase + i) * kD + h0);
      v0 = fmaf(a0, v0, bf2f(q.x));
      v1 = fmaf(a1, v1, bf2f(q.y));
      v2 = fmaf(a2, v2, bf2f(q.z));
      v3 = fmaf(a3, v3, bf2f(q.w));
      bh4 o;
      o.a = __float2bfloat16(v0);
      o.b = __float2bfloat16(v1);
      o.c = __float2bfloat16(v2);
      o.d = __float2bfloat16(v3);
      *reinterpret_cast<bh4*>(&cxs[i * PADH + h0]) = o;
    }
  }
  __syncthreads();
  // ---- pass 2: per-row stats (8 lanes per row) ----
  {
    int row = t >> 3, j = t & 7;
    float s1 = 0.f, s2 = 0.f;
#pragma unroll
    for (int ch = 0; ch < 16; ++ch) {
      bf16x8 vv = *reinterpret_cast<const bf16x8*>(
          &cxs[row * PADH + j * 128 + ch * 8]);
#pragma unroll
      for (int e = 0; e < 8; ++e) {
        float f = bf2f(vv[e]);
        s1 += f;
        s2 += f * f;
      }
    }
    s1 += __shfl_xor(s1, 1); s2 += __shfl_xor(s2, 1);
    s1 += __shfl_xor(s1, 2); s2 += __shfl_xor(s2, 2);
    s1 += __shfl_xor(s1, 4); s2 += __shfl_xor(s2, 4);
    if (j == 0) {
      float mu = s1 * (1.0f / kD);
      float var = s2 * (1.0f / kD) - mu * mu;
      smu[row] = mu;
      srs[row] = rsqrtf(var + kEps);
    }
  }
  __syncthreads();
  // ---- pass 3: LN + global write (pass-1 mapping, coalesced) ----
  {
    const float4 wv = *reinterpret_cast<const float4*>(lnw + h0);
    const float4 bv = *reinterpret_cast<const float4*>(lnb + h0);
#pragma unroll 4
    for (int i = 0; i < kChunk; ++i) {
      short4 q = *reinterpret_cast<const short4*>(&cxs[i * PADH + h0]);
      float mu = smu[i], rs = srs[i];
      bh4 o;
      o.a = __float2bfloat16((bf2f(q.x) - mu) * rs * wv.x + bv.x);
      o.b = __float2bfloat16((bf2f(q.y) - mu) * rs * wv.y + bv.y);
      o.c = __float2bfloat16((bf2f(q.z) - mu) * rs * wv.z + bv.z);
      o.d = __float2bfloat16((bf2f(q.w) - mu) * rs * wv.w + bv.w);
      *reinterpret_cast<bh4*>(cxn + (rowbase + i) * kD + h0) = o;
    }
  }
}

// ---------------- final: LN(gpre) -> sigmoid -> blend ---------------------
__global__ __launch_bounds__(256) void k_final(
    const __hip_bfloat16* __restrict__ gpre, const __hip_bfloat16* __restrict__ res,
    const __hip_bfloat16* __restrict__ outp, const float* __restrict__ w,
    const float* __restrict__ b, float* __restrict__ y) {
  int row = blockIdx.x;
  int t = threadIdx.x;
  short4 q = reinterpret_cast<const short4*>(gpre + (size_t)row * kD)[t];
  float vv[4] = {bf2f(q.x), bf2f(q.y), bf2f(q.z), bf2f(q.w)};
  float s1 = vv[0] + vv[1] + vv[2] + vv[3];
  float s2 = vv[0] * vv[0] + vv[1] * vv[1] + vv[2] * vv[2] + vv[3] * vv[3];
  blockReduce2(s1, s2);
  float mu = s1 * (1.0f / kD);
  float var = s2 * (1.0f / kD) - mu * mu;
  float rs = rsqrtf(var + kEps);
  float4 wv = reinterpret_cast<const float4*>(w)[t];
  float4 bv = reinterpret_cast<const float4*>(b)[t];
  short4 r4 = reinterpret_cast<const short4*>(res + (size_t)row * kD)[t];
  short4 o4 = reinterpret_cast<const short4*>(outp + (size_t)row * kD)[t];
  float rr[4] = {bf2f(r4.x), bf2f(r4.y), bf2f(r4.z), bf2f(r4.w)};
  float oo[4] = {bf2f(o4.x), bf2f(o4.y), bf2f(o4.z), bf2f(o4.w)};
  float ww[4] = {wv.x, wv.y, wv.z, wv.w};
  float bb[4] = {bv.x, bv.y, bv.z, bv.w};
  float4 out;
  float* op = &out.x;
#pragma unroll
  for (int i = 0; i < 4; ++i) {
    float z = (vv[i] - mu) * rs * ww[i] + bb[i];
    float g = 1.0f / (1.0f + expf(-z));
    op[i] = rr[i] + g * (oo[i] - rr[i]);
  }
  reinterpret_cast<float4*>(y + (size_t)row * kD)[t] = out;
}

}  // namespace

extern "C" void kernel_launch(void* const* d_in, const int* in_sizes, int n_in,
                              void* d_out, int out_size, void* d_ws,
                              size_t ws_size, hipStream_t stream) {
  const float* x = (const float*)d_in[0];
  const float* Wt = (const float*)d_in[1];
  const float* Wo = (const float*)d_in[2];
  const float* Wg = (const float*)d_in[3];
  const float* bg = (const float*)d_in[4];
  const float* ln1w = (const float*)d_in[5];
  const float* ln1b = (const float*)d_in[6];
  const float* lncw = (const float*)d_in[7];
  const float* lncb = (const float*)d_in[8];
  const float* lngw = (const float*)d_in[9];
  const float* lngb = (const float*)d_in[10];
  float* y = (float*)d_out;

  char* ws = (char*)d_ws;
  size_t off = 0;
  auto alloc = [&](size_t bytes) {
    char* p = ws + off;
    off += (bytes + 255) & ~(size_t)255;
    return p;
  };
  __hip_bfloat16* xnb = (__hip_bfloat16*)alloc((size_t)kN * kD * 2);  // _x (res)
  __hip_bfloat16* ub = (__hip_bfloat16*)alloc((size_t)kN * kD * 2);   // u -> gpre
  __hip_bfloat16* outb = (__hip_bfloat16*)alloc((size_t)kN * kD * 2); // out
  __hip_bfloat16* cxn = (__hip_bfloat16*)alloc((size_t)kN * kD * 2);  // LN(cx)
  __hip_bfloat16* WtT = (__hip_bfloat16*)alloc((size_t)kD * kD * 2);
  __hip_bfloat16* WoT = (__hip_bfloat16*)alloc((size_t)kD * kD * 2);
  __hip_bfloat16* WgT = (__hip_bfloat16*)alloc((size_t)kD * 2 * kD * 2);
  float* decay = (float*)alloc(kD * 4);
  float* dbeta = (float*)alloc(kD * 4);
  float* aL = (float*)alloc(kD * 4);
  float* ends = (float*)alloc((size_t)kB * kNChunk * kD * 4);   // 2MB
  float* carry = (float*)alloc((size_t)kB * kNChunk * kD * 4);  // 2MB

  const int nwg = (kD / 256) * (kN / 256);  // 4 * 64 = 256, % 8 == 0

  // fused: LN(x) + decay + weight transpose-casts (one launch)
  k_prep_ln<<<kN + 4 + 4096, 256, 0, stream>>>(
      x, ln1w, ln1b, xnb, Wt, Wo, Wg, WtT, WoT, WgT, decay, dbeta, aL);
  // u = (_x @ Wt) * decay_beta (bf16 out) + fused scan_ends (32-row chunks)
  k_mfma_gemm<<<nwg, 512, 0, stream>>>(xnb, nullptr, WtT, kD, nullptr, ub,
                                       dbeta, nullptr, ends, decay);
  // scan carries (64 chunks)
  k_scan_carry<<<(kB * kD) / 256, 256, 0, stream>>>(ends, aL, carry);
  // fused rescan + LN: u -> cxn = LN(cx) directly (cx never materialized)
  k_scan_apply_ln<<<kB * kNChunk, 256, 0, stream>>>(ub, decay, carry, lncw,
                                                    lncb, cxn);
  // out = LN(cx) @ Wo  (bf16 out)
  k_mfma_gemm<<<nwg, 512, 0, stream>>>(cxn, nullptr, WoT, kD, nullptr, outb,
                                       nullptr, nullptr, nullptr, nullptr);
  // gpre = concat(_x, out) @ Wg + bg  (bf16 out, overwrites ub; u dead)
  k_mfma_gemm<<<nwg, 512, 0, stream>>>(xnb, outb, WgT, 2 * kD, nullptr, ub,
                                       nullptr, bg, nullptr, nullptr);
  // y = res + sigmoid(LN(gpre)) * (out - res)
  k_final<<<kN, 256, 0, stream>>>(ub, xnb, outb, lngw, lngb, y);
}